// Round 11
// baseline (158.470 us; speedup 1.0000x reference)
//
#include <hip/hip_runtime.h>
#include <hip/hip_bf16.h>

// Problem constants (match reference)
#define RR 3
#define NN 8192
#define BB 4096
#define IN_DIM 256
#define HID 128
#define OUT 64
#define CAPD 128     // padded list capacity (unique nbr nodes ~ Binom(3224,0.01) ~ 32±5.7)
#define EPS 1e-5f
#define MWN (NN / 64)   // 128 mask words over node space

// ---- K1: blocks 0..255 = BN1 per-column stats -> affine consts; block 256 = prep ----
__global__ __launch_bounds__(256) void k1_bn1_prep_k(const float* __restrict__ feat,
                                                     const int* __restrict__ bn,
                                                     const float* __restrict__ g1,
                                                     const float* __restrict__ b1,
                                                     float* __restrict__ af,
                                                     float* __restrict__ bfv,
                                                     unsigned long long* __restrict__ memb,
                                                     unsigned short* __restrict__ rankg,
                                                     unsigned short* __restrict__ nodeof,
                                                     float* __restrict__ multf,
                                                     int* __restrict__ Ucnt,
                                                     unsigned short* __restrict__ pos2slot) {
    __shared__ int smult[NN];                 // 32 KB (prep block only)
    __shared__ unsigned short srank[NN];      // 16 KB
    __shared__ unsigned long long smemb[MWN]; // 1 KB
    __shared__ int sbase[MWN + 1];
    __shared__ float ps[4], pq[4];
    int t = threadIdx.x;
    if (blockIdx.x < IN_DIM) {
        // BN1 stats for column c
        int c = blockIdx.x;
        float s = 0.f, q = 0.f;
        for (int i = t; i < BB; i += 256) {
            float v = feat[(size_t)bn[i] * IN_DIM + c];
            s += v; q += v * v;
        }
        int lane = t & 63, wv = t >> 6;
        for (int o = 32; o; o >>= 1) { s += __shfl_down(s, o); q += __shfl_down(q, o); }
        if (lane == 0) { ps[wv] = s; pq[wv] = q; }
        __syncthreads();
        if (t == 0) {
            float S = ps[0] + ps[1] + ps[2] + ps[3];
            float Q = pq[0] + pq[1] + pq[2] + pq[3];
            float m = S / BB;
            float rs = rsqrtf(Q / BB - m * m + EPS);   // biased variance
            float a = rs * g1[c];
            af[c]  = a;
            bfv[c] = b1[c] - m * a;
        }
        return;
    }
    // ---- prep (single block, 256 threads) ----
    for (int u = t; u < NN; u += 256) smult[u] = 0;
    __syncthreads();
    for (int i = t; i < BB; i += 256) atomicAdd(&smult[bn[i]], 1);
    __syncthreads();
    if (t < MWN) {
        unsigned long long w = 0;
        for (int b = 0; b < 64; ++b) if (smult[t * 64 + b]) w |= (1ull << b);
        smemb[t] = w;
        memb[t] = w;
    }
    __syncthreads();
    if (t == 0) {
        int acc = 0;
        for (int m = 0; m < MWN; ++m) { sbase[m] = acc; acc += (int)__popcll(smemb[m]); }
        sbase[MWN] = acc;
        *Ucnt = acc;
    }
    __syncthreads();
    if (t < MWN) {
        unsigned long long w = smemb[t];
        int p = sbase[t];
        while (w) {
            int b = __builtin_ctzll(w); w &= w - 1;
            int u = t * 64 + b;
            srank[u] = (unsigned short)p;
            rankg[u] = (unsigned short)p;
            nodeof[p] = (unsigned short)u;
            multf[p]  = (float)smult[u];
            ++p;
        }
    }
    __syncthreads();
    for (int i = t; i < BB; i += 256) pos2slot[i] = srank[bn[i]];
}

// ---- build per (r, slot): coalesced row read -> bits -> AND membership -> packed list ----
__global__ __launch_bounds__(256) void build_k(const float* __restrict__ adj,
                                               const unsigned short* __restrict__ nodeof,
                                               const int* __restrict__ Ucnt,
                                               const unsigned long long* __restrict__ memb,
                                               const unsigned short* __restrict__ rankg,
                                               const float* __restrict__ multf,
                                               unsigned* __restrict__ cols,
                                               int* __restrict__ cnt,
                                               float* __restrict__ dinv) {
    int blk = blockIdx.x;                   // r*4096 + s
    int r = blk >> 12, s = blk & (BB - 1);
    if (s >= *Ucnt) return;
    int u = nodeof[s];
    __shared__ unsigned char nib[2048];
    __shared__ unsigned int rawb[256];
    __shared__ unsigned long long sel[MWN];
    __shared__ int sbase[MWN + 1];
    __shared__ float pdeg[4];
    int t = threadIdx.x;
    // phase A: coalesced read of the 8192-float adjacency row; compress to bits
    const float4* ar4 = (const float4*)(adj + ((size_t)r * NN + u) * NN);
    #pragma unroll
    for (int ch = 0; ch < 8; ++ch) {
        float4 v = ar4[ch * 256 + t];
        nib[ch * 256 + t] = (unsigned char)((v.x != 0.f) | ((v.y != 0.f) << 1) |
                                            ((v.z != 0.f) << 2) | ((v.w != 0.f) << 3));
    }
    __syncthreads();
    {   // assemble u32 word t: cols [32t, 32t+32)
        unsigned long long x = *(const unsigned long long*)&nib[t * 8];
        x = (x | (x >> 4))  & 0x00FF00FF00FF00FFull;
        x = (x | (x >> 8))  & 0x0000FFFF0000FFFFull;
        x = (x | (x >> 16));
        rawb[t] = (unsigned int)x;
    }
    __syncthreads();
    // phase B: select member columns = raw & memb
    if (t < MWN) {
        unsigned long long w = ((unsigned long long)rawb[2 * t + 1] << 32) | rawb[2 * t];
        sel[t] = w & memb[t];
    }
    __syncthreads();
    // phase C: exclusive scan of word popcounts (wave 0, 2 words/lane)
    if (t < 64) {
        int p0 = (int)__popcll(sel[2 * t]);
        int p1 = (int)__popcll(sel[2 * t + 1]);
        int x = p0 + p1, xs = x;
        for (int o = 1; o < 64; o <<= 1) { int y = __shfl_up(xs, o); if (t >= o) xs += y; }
        sbase[2 * t]     = xs - x;
        sbase[2 * t + 1] = xs - p1;
        if (t == 63) sbase[MWN] = xs;
    }
    __syncthreads();
    // phase D: emit packed (slot<<13)|node list + multiplicity-weighted degree
    float wdeg = 0.f;
    if (t < MWN) {
        unsigned long long w = sel[t];
        int p = sbase[t];
        unsigned* cb = cols + (size_t)blk * CAPD;
        while (w) {
            int b = __builtin_ctzll(w); w &= w - 1;
            int v = t * 64 + b;              // node id (13 bits)
            int rv = rankg[v];               // slot id (12 bits)
            if (p < CAPD) cb[p] = ((unsigned)rv << 13) | (unsigned)v;
            wdeg += multf[rv];
            ++p;
        }
    }
    int lane = t & 63, wv = t >> 6;
    for (int o = 32; o; o >>= 1) wdeg += __shfl_down(wdeg, o);
    if (lane == 0) pdeg[wv] = wdeg;
    __syncthreads();
    if (t == 0) {
        int tot = sbase[MWN];
        cnt[blk] = tot < CAPD ? tot : CAPD;
        dinv[blk] = rsqrtf(pdeg[0] + pdeg[1] + pdeg[2] + pdeg[3] + 1.0f);  // +1 from eye
    }
}

// ---- z1: per unique slot, z1[s] = (feat[nodeof[s]] * af) @ w1 ; block0 also c1 = bfv @ w1 ----
__global__ __launch_bounds__(256) void z1_k(const float* __restrict__ feat,
                                            const unsigned short* __restrict__ nodeof,
                                            const int* __restrict__ Ucnt,
                                            const float* __restrict__ af,
                                            const float* __restrict__ bfv,
                                            const float* __restrict__ w1,
                                            float* __restrict__ z1,
                                            float* __restrict__ c1) {
    int base = blockIdx.x << 4;           // 16 slots/block
    int U = *Ucnt;
    int t = threadIdx.x;
    if (base < U) {
        __shared__ float ys[16][IN_DIM];  // 16 KB
        float a = af[t];
        #pragma unroll
        for (int s = 0; s < 16; ++s) {
            int slot = base + s;
            ys[s][t] = (slot < U) ? feat[(size_t)nodeof[slot] * IN_DIM + t] * a : 0.f;
        }
        __syncthreads();
        int c = t & 127, g = t >> 7;      // g in {0,1}: slots g*8..g*8+7
        float acc[8] = {0.f};
        for (int k = 0; k < IN_DIM; ++k) {
            float wvl = w1[k * HID + c];
            #pragma unroll
            for (int j = 0; j < 8; ++j) acc[j] += ys[g * 8 + j][k] * wvl;
        }
        #pragma unroll
        for (int j = 0; j < 8; ++j) {
            int slot = base + g * 8 + j;
            if (slot < U) z1[(size_t)slot * HID + c] = acc[j];
        }
    }
    if (blockIdx.x == 0 && t < HID) {     // c1 = bfv @ w1
        float cc = 0.f;
        for (int k = 0; k < IN_DIM; ++k) cc += bfv[k] * w1[k * HID + t];
        c1[t] = cc;
    }
}

// ---- fused agg(z1)+act+GEMM(w2): 16 slots/block -> z2 (pre-elu of layer2 GEMM input path) ----
__global__ __launch_bounds__(256) void agg1z_k(const float* __restrict__ z1,
                                               const unsigned* __restrict__ cols,
                                               const int* __restrict__ cnt,
                                               const float* __restrict__ dinv,
                                               const float* __restrict__ multf,
                                               const int* __restrict__ Ucnt,
                                               const float* __restrict__ c1,
                                               const float* __restrict__ w2,
                                               float* __restrict__ z2) {
    int blk = blockIdx.x;                 // r*256 + chunk
    int r = blk >> 8, base = (blk & 255) << 4;
    int U = *Ucnt;
    if (base >= U) return;
    int t = threadIdx.x, lane = t & 63, wv = t >> 6;
    __shared__ unsigned short scl[16][CAPD];     // 4 KB (slot ids)
    __shared__ float swl[16][CAPD];              // 8 KB
    __shared__ float ys[16][HID];                // 8 KB (activated h1 rows)
    __shared__ float sdii[16], ssw[16];
    __shared__ int sn[16];
    for (int s16 = wv; s16 < 16; s16 += 4) {
        int slot = base + s16;
        int n = (slot < U) ? cnt[(r << 12) + slot] : 0;
        if (lane == 0) { sn[s16] = n; sdii[s16] = (slot < U) ? dinv[(r << 12) + slot] : 0.f; }
        size_t cb = ((size_t)(r << 12) + slot) * CAPD;
        float swsum = 0.f;
        for (int idx = lane; idx < n; idx += 64) {
            unsigned e = cols[cb + idx];
            int sl = e >> 13;
            scl[s16][idx] = (unsigned short)sl;
            float w = multf[sl] * dinv[(r << 12) + sl];
            swl[s16][idx] = w;
            swsum += w;
        }
        for (int o = 32; o; o >>= 1) swsum += __shfl_down(swsum, o);
        if (lane == 0) ssw[s16] = swsum;
    }
    __syncthreads();
    // aggregate z1 (HID cols, float2/lane) + c1 row + act -> ys
    int c2 = lane << 1;
    for (int j = 0; j < 4; ++j) {
        int s16 = (wv << 2) + j;
        int slot = base + s16;
        if (slot >= U) { ys[s16][c2] = 0.f; ys[s16][c2 + 1] = 0.f; continue; }
        int n = sn[s16];
        float di = sdii[s16];
        float2 v = ((const float2*)(z1 + (size_t)slot * HID))[lane];
        float ax = di * v.x, ay = di * v.y;
        #pragma unroll 4
        for (int k = 0; k < n; ++k) {
            float w = swl[s16][k];
            float2 x = ((const float2*)(z1 + (size_t)scl[s16][k] * HID))[lane];
            ax += w * x.x; ay += w * x.y;
        }
        float f = di * (di + ssw[s16]);
        float zx = ax * di + f * c1[c2];
        float zy = ay * di + f * c1[c2 + 1];
        float ex = zx > 0.f ? zx : expm1f(zx);           // elu
        float ey = zy > 0.f ? zy : expm1f(zy);
        ys[s16][c2]     = 1.f / (1.f + expf(-ex));       // sigmoid
        ys[s16][c2 + 1] = 1.f / (1.f + expf(-ey));
    }
    __syncthreads();
    // GEMM by w2: thread -> col c = t&63, group g = t>>6 covers slots g*4..g*4+3
    int c = t & 63, g = t >> 6;
    float acc[4] = {0.f};
    for (int k = 0; k < HID; ++k) {
        float wvl = w2[k * OUT + c];
        #pragma unroll
        for (int j = 0; j < 4; ++j) acc[j] += ys[g * 4 + j][k] * wvl;
    }
    #pragma unroll
    for (int j = 0; j < 4; ++j) {
        int slot = base + g * 4 + j;
        if (slot < U) z2[((size_t)(r << 12) + slot) * OUT + c] = acc[j];
    }
}

// ---- agg2+elu: aggregate z2 (OUT cols, 1 col/lane) -> h2 ----
__global__ __launch_bounds__(256) void agg2act_k(const float* __restrict__ z2,
                                                 const unsigned* __restrict__ cols,
                                                 const int* __restrict__ cnt,
                                                 const float* __restrict__ dinv,
                                                 const float* __restrict__ multf,
                                                 const int* __restrict__ Ucnt,
                                                 float* __restrict__ h2) {
    int blk = blockIdx.x;                 // r*256 + chunk
    int r = blk >> 8, base = (blk & 255) << 4;
    int U = *Ucnt;
    if (base >= U) return;
    int t = threadIdx.x, lane = t & 63, wv = t >> 6;
    __shared__ unsigned short scl[16][CAPD];     // 4 KB
    __shared__ float swl[16][CAPD];              // 8 KB
    __shared__ float sdii[16];
    __shared__ int sn[16];
    for (int s16 = wv; s16 < 16; s16 += 4) {
        int slot = base + s16;
        int n = (slot < U) ? cnt[(r << 12) + slot] : 0;
        if (lane == 0) { sn[s16] = n; sdii[s16] = (slot < U) ? dinv[(r << 12) + slot] : 0.f; }
        size_t cb = ((size_t)(r << 12) + slot) * CAPD;
        for (int idx = lane; idx < n; idx += 64) {
            unsigned e = cols[cb + idx];
            int sl = e >> 13;
            scl[s16][idx] = (unsigned short)sl;
            swl[s16][idx] = multf[sl] * dinv[(r << 12) + sl];
        }
    }
    __syncthreads();
    const float* z2r = z2 + ((size_t)(r << 12)) * OUT;
    for (int j = 0; j < 4; ++j) {
        int s16 = (wv << 2) + j;
        int slot = base + s16;
        if (slot >= U) continue;
        int n = sn[s16];
        float di = sdii[s16];
        float acc = di * z2r[(size_t)slot * OUT + lane];
        #pragma unroll 4
        for (int k = 0; k < n; ++k) {
            acc += swl[s16][k] * z2r[(size_t)scl[s16][k] * OUT + lane];
        }
        float z = acc * di;
        h2[((size_t)(r << 12) + slot) * OUT + lane] = z > 0.f ? z : expm1f(z);  // elu
    }
}

// ---- BN2 stats per (relation, column): multiplicity-weighted over slots ----
__global__ __launch_bounds__(256) void bn2_stats_k(const float* __restrict__ h2,
                                                   const float* __restrict__ multf,
                                                   const int* __restrict__ Ucnt,
                                                   float* __restrict__ m2,
                                                   float* __restrict__ rs2) {
    int ro = blockIdx.x;             // r*OUT + o
    int r = ro >> 6, o = ro & (OUT - 1);
    int U = *Ucnt;
    float s = 0.f, q = 0.f;
    for (int sl = threadIdx.x; sl < U; sl += 256) {
        float m = multf[sl];
        float v = h2[(size_t)((r << 12) + sl) * OUT + o];
        s += m * v; q += m * v * v;
    }
    int lane = threadIdx.x & 63, wv = threadIdx.x >> 6;
    for (int off = 32; off; off >>= 1) { s += __shfl_down(s, off); q += __shfl_down(q, off); }
    __shared__ float ps[4], pq[4];
    if (lane == 0) { ps[wv] = s; pq[wv] = q; }
    __syncthreads();
    if (threadIdx.x == 0) {
        float S = ps[0] + ps[1] + ps[2] + ps[3];
        float Q = pq[0] + pq[1] + pq[2] + pq[3];
        float m = S / BB;                 // sum of mult == BB positions
        float v = Q / BB - m * m;
        m2[ro] = m;
        rs2[ro] = rsqrtf(v + EPS);
    }
}

// ---- finalize: out[i] = relu(mean_r BN2(h2[r, slot(i)])) ----
__global__ __launch_bounds__(256) void finalize_k(const float* __restrict__ h2,
                                                  const unsigned short* __restrict__ pos2slot,
                                                  const float* __restrict__ m2,
                                                  const float* __restrict__ rs2,
                                                  const float* __restrict__ g2,
                                                  const float* __restrict__ b2,
                                                  float* __restrict__ out) {
    int idx = blockIdx.x * 256 + threadIdx.x;  // i*OUT + o
    if (idx >= BB * OUT) return;
    int i = idx >> 6, o = idx & (OUT - 1);
    int sl = pos2slot[i];
    float s = 0.f;
    for (int r = 0; r < RR; ++r) {
        float v = h2[(size_t)((r << 12) + sl) * OUT + o];
        s += (v - m2[r * OUT + o]) * rs2[r * OUT + o] * g2[o] + b2[o];
    }
    s *= (1.0f / RR);
    out[idx] = s > 0.f ? s : 0.f;
}

extern "C" void kernel_launch(void* const* d_in, const int* in_sizes, int n_in,
                              void* d_out, int out_size, void* d_ws, size_t ws_size,
                              hipStream_t stream) {
    const float* feat = (const float*)d_in[0];
    const float* adj  = (const float*)d_in[1];
    const int*   bn   = (const int*)d_in[2];
    const float* w1   = (const float*)d_in[3];
    const float* w2   = (const float*)d_in[4];
    const float* g1   = (const float*)d_in[5];
    const float* b1   = (const float*)d_in[6];
    const float* g2   = (const float*)d_in[7];
    const float* b2   = (const float*)d_in[8];
    float* out = (float*)d_out;

    // workspace layout (256-aligned offsets)
    char* ws = (char*)d_ws;
    size_t off = 0;
    auto alloc = [&](size_t bytes) { size_t o = off; off += (bytes + 255) & ~(size_t)255; return o; };
    unsigned long long* memb = (unsigned long long*)(ws + alloc(MWN * 8));      // 1 KB
    unsigned short* rankg    = (unsigned short*)(ws + alloc(NN * 2));           // 16 KB
    unsigned short* nodeof   = (unsigned short*)(ws + alloc(BB * 2));           // 8 KB
    float* multf             = (float*)(ws + alloc(BB * 4));                    // 16 KB
    int* Ucnt                = (int*)(ws + alloc(4));
    unsigned short* pos2slot = (unsigned short*)(ws + alloc(BB * 2));           // 8 KB
    float* af                = (float*)(ws + alloc(IN_DIM * 4));
    float* bfv               = (float*)(ws + alloc(IN_DIM * 4));
    float* c1                = (float*)(ws + alloc(HID * 4));
    float* m2                = (float*)(ws + alloc(RR * OUT * 4));
    float* rs2               = (float*)(ws + alloc(RR * OUT * 4));
    unsigned* cols           = (unsigned*)(ws + alloc((size_t)RR * BB * CAPD * 4)); // 6.3 MB
    int* cnt                 = (int*)(ws + alloc((size_t)RR * BB * 4));         // 48 KB
    float* dinv              = (float*)(ws + alloc((size_t)RR * BB * 4));       // 48 KB
    float* z1                = (float*)(ws + alloc((size_t)BB * HID * 4));      // 2 MB
    float* z2                = (float*)(ws + alloc((size_t)RR * BB * OUT * 4)); // 3.1 MB
    float* h2                = (float*)(ws + alloc((size_t)RR * BB * OUT * 4)); // 3.1 MB

    k1_bn1_prep_k<<<IN_DIM + 1, 256, 0, stream>>>(feat, bn, g1, b1, af, bfv,
                                                  memb, rankg, nodeof, multf, Ucnt, pos2slot);
    build_k<<<RR * BB, 256, 0, stream>>>(adj, nodeof, Ucnt, memb, rankg, multf, cols, cnt, dinv);
    z1_k<<<BB / 16, 256, 0, stream>>>(feat, nodeof, Ucnt, af, bfv, w1, z1, c1);
    agg1z_k<<<RR * (BB / 16), 256, 0, stream>>>(z1, cols, cnt, dinv, multf, Ucnt, c1, w2, z2);
    agg2act_k<<<RR * (BB / 16), 256, 0, stream>>>(z2, cols, cnt, dinv, multf, Ucnt, h2);
    bn2_stats_k<<<RR * OUT, 256, 0, stream>>>(h2, multf, Ucnt, m2, rs2);
    finalize_k<<<(BB * OUT + 255) / 256, 256, 0, stream>>>(h2, pos2slot, m2, rs2, g2, b2, out);
}

// Round 12
// 153.780 us; speedup vs baseline: 1.0305x; 1.0305x over previous
//
#include <hip/hip_runtime.h>
#include <hip/hip_bf16.h>

// Problem constants (match reference)
#define RR 3
#define NN 8192
#define BB 4096
#define IN_DIM 256
#define HID 128
#define OUT 64
#define CAPD 128     // padded list capacity (unique nbr nodes ~ Binom(3224,0.01) ~ 32±5.7)
#define EPS 1e-5f
#define MWN (NN / 64)   // 128 mask words over node space

// ---- K1: blocks 0..255 = BN1 per-column stats -> affine consts; block 256 = prep ----
__global__ __launch_bounds__(256) void k1_bn1_prep_k(const float* __restrict__ feat,
                                                     const int* __restrict__ bn,
                                                     const float* __restrict__ g1,
                                                     const float* __restrict__ b1,
                                                     float* __restrict__ af,
                                                     float* __restrict__ bfv,
                                                     unsigned long long* __restrict__ memb,
                                                     unsigned short* __restrict__ rankg,
                                                     unsigned short* __restrict__ nodeof,
                                                     float* __restrict__ multf,
                                                     int* __restrict__ Ucnt,
                                                     unsigned short* __restrict__ pos2slot) {
    __shared__ int smult[NN];                 // 32 KB (prep block only)
    __shared__ unsigned short srank[NN];      // 16 KB
    __shared__ unsigned long long smemb[MWN]; // 1 KB
    __shared__ int sbase[MWN + 1];
    __shared__ float ps[4], pq[4];
    int t = threadIdx.x;
    if (blockIdx.x < IN_DIM) {
        // BN1 stats for column c
        int c = blockIdx.x;
        float s = 0.f, q = 0.f;
        for (int i = t; i < BB; i += 256) {
            float v = feat[(size_t)bn[i] * IN_DIM + c];
            s += v; q += v * v;
        }
        int lane = t & 63, wv = t >> 6;
        for (int o = 32; o; o >>= 1) { s += __shfl_down(s, o); q += __shfl_down(q, o); }
        if (lane == 0) { ps[wv] = s; pq[wv] = q; }
        __syncthreads();
        if (t == 0) {
            float S = ps[0] + ps[1] + ps[2] + ps[3];
            float Q = pq[0] + pq[1] + pq[2] + pq[3];
            float m = S / BB;
            float rs = rsqrtf(Q / BB - m * m + EPS);   // biased variance
            float a = rs * g1[c];
            af[c]  = a;
            bfv[c] = b1[c] - m * a;
        }
        return;
    }
    // ---- prep (single block, 256 threads) ----
    for (int u = t; u < NN; u += 256) smult[u] = 0;
    __syncthreads();
    for (int i = t; i < BB; i += 256) atomicAdd(&smult[bn[i]], 1);
    __syncthreads();
    if (t < MWN) {
        unsigned long long w = 0;
        for (int b = 0; b < 64; ++b) if (smult[t * 64 + b]) w |= (1ull << b);
        smemb[t] = w;
        memb[t] = w;
    }
    __syncthreads();
    if (t == 0) {
        int acc = 0;
        for (int m = 0; m < MWN; ++m) { sbase[m] = acc; acc += (int)__popcll(smemb[m]); }
        sbase[MWN] = acc;
        *Ucnt = acc;
    }
    __syncthreads();
    if (t < MWN) {
        unsigned long long w = smemb[t];
        int p = sbase[t];
        while (w) {
            int b = __builtin_ctzll(w); w &= w - 1;
            int u = t * 64 + b;
            srank[u] = (unsigned short)p;
            rankg[u] = (unsigned short)p;
            nodeof[p] = (unsigned short)u;
            multf[p]  = (float)smult[u];
            ++p;
        }
    }
    __syncthreads();
    for (int i = t; i < BB; i += 256) pos2slot[i] = srank[bn[i]];
}

// ---- build per (r, slot): coalesced row read -> bits -> AND membership -> packed list ----
__global__ __launch_bounds__(256) void build_k(const float* __restrict__ adj,
                                               const unsigned short* __restrict__ nodeof,
                                               const int* __restrict__ Ucnt,
                                               const unsigned long long* __restrict__ memb,
                                               const unsigned short* __restrict__ rankg,
                                               const float* __restrict__ multf,
                                               unsigned* __restrict__ cols,
                                               int* __restrict__ cnt,
                                               float* __restrict__ dinv) {
    int blk = blockIdx.x;                   // r*4096 + s
    int r = blk >> 12, s = blk & (BB - 1);
    if (s >= *Ucnt) return;
    int u = nodeof[s];
    __shared__ unsigned char nib[2048];
    __shared__ unsigned int rawb[256];
    __shared__ unsigned long long sel[MWN];
    __shared__ int sbase[MWN + 1];
    __shared__ float pdeg[4];
    int t = threadIdx.x;
    // phase A: coalesced read of the 8192-float adjacency row; compress to bits
    const float4* ar4 = (const float4*)(adj + ((size_t)r * NN + u) * NN);
    #pragma unroll
    for (int ch = 0; ch < 8; ++ch) {
        float4 v = ar4[ch * 256 + t];
        nib[ch * 256 + t] = (unsigned char)((v.x != 0.f) | ((v.y != 0.f) << 1) |
                                            ((v.z != 0.f) << 2) | ((v.w != 0.f) << 3));
    }
    __syncthreads();
    {   // assemble u32 word t: cols [32t, 32t+32)
        unsigned long long x = *(const unsigned long long*)&nib[t * 8];
        x = (x | (x >> 4))  & 0x00FF00FF00FF00FFull;
        x = (x | (x >> 8))  & 0x0000FFFF0000FFFFull;
        x = (x | (x >> 16));
        rawb[t] = (unsigned int)x;
    }
    __syncthreads();
    // phase B: select member columns = raw & memb
    if (t < MWN) {
        unsigned long long w = ((unsigned long long)rawb[2 * t + 1] << 32) | rawb[2 * t];
        sel[t] = w & memb[t];
    }
    __syncthreads();
    // phase C: exclusive scan of word popcounts (wave 0, 2 words/lane)
    if (t < 64) {
        int p0 = (int)__popcll(sel[2 * t]);
        int p1 = (int)__popcll(sel[2 * t + 1]);
        int x = p0 + p1, xs = x;
        for (int o = 1; o < 64; o <<= 1) { int y = __shfl_up(xs, o); if (t >= o) xs += y; }
        sbase[2 * t]     = xs - x;
        sbase[2 * t + 1] = xs - p1;
        if (t == 63) sbase[MWN] = xs;
    }
    __syncthreads();
    // phase D: emit packed (slot<<13)|node list + multiplicity-weighted degree
    float wdeg = 0.f;
    if (t < MWN) {
        unsigned long long w = sel[t];
        int p = sbase[t];
        unsigned* cb = cols + (size_t)blk * CAPD;
        while (w) {
            int b = __builtin_ctzll(w); w &= w - 1;
            int v = t * 64 + b;              // node id (13 bits)
            int rv = rankg[v];               // slot id (12 bits)
            if (p < CAPD) cb[p] = ((unsigned)rv << 13) | (unsigned)v;
            wdeg += multf[rv];
            ++p;
        }
    }
    int lane = t & 63, wv = t >> 6;
    for (int o = 32; o; o >>= 1) wdeg += __shfl_down(wdeg, o);
    if (lane == 0) pdeg[wv] = wdeg;
    __syncthreads();
    if (t == 0) {
        int tot = sbase[MWN];
        cnt[blk] = tot < CAPD ? tot : CAPD;
        dinv[blk] = rsqrtf(pdeg[0] + pdeg[1] + pdeg[2] + pdeg[3] + 1.0f);  // +1 from eye
    }
}

// ---- fused agg1+mlp1: 16 slots/block; agg raw feat + affine -> LDS -> GEMM+act ----
__global__ __launch_bounds__(256) void aggmlp1_k(const float* __restrict__ feat,
                                                 const unsigned* __restrict__ cols,
                                                 const int* __restrict__ cnt,
                                                 const float* __restrict__ dinv,
                                                 const float* __restrict__ multf,
                                                 const unsigned short* __restrict__ nodeof,
                                                 const int* __restrict__ Ucnt,
                                                 const float* __restrict__ af,
                                                 const float* __restrict__ bfv,
                                                 const float* __restrict__ w1,
                                                 float* __restrict__ h1) {
    int blk = blockIdx.x;                 // r*256 + chunk
    int r = blk >> 8, base = (blk & 255) << 4;
    int U = *Ucnt;
    if (base >= U) return;
    int t = threadIdx.x, lane = t & 63, wv = t >> 6;
    __shared__ unsigned short snode[16][CAPD];   // 4 KB
    __shared__ float swl[16][CAPD];              // 8 KB
    __shared__ float ys[16][IN_DIM];             // 16 KB
    __shared__ float sdii[16], ssw[16];
    __shared__ int sn[16];
    // stage 16 lists (wave wv handles s16 = wv, wv+4, wv+8, wv+12)
    for (int s16 = wv; s16 < 16; s16 += 4) {
        int slot = base + s16;
        int n = (slot < U) ? cnt[(r << 12) + slot] : 0;
        if (lane == 0) { sn[s16] = n; sdii[s16] = (slot < U) ? dinv[(r << 12) + slot] : 0.f; }
        size_t cb = ((size_t)(r << 12) + slot) * CAPD;
        float swsum = 0.f;
        for (int idx = lane; idx < n; idx += 64) {
            unsigned e = cols[cb + idx];
            int sl = e >> 13;
            snode[s16][idx] = (unsigned short)(e & 8191u);
            float w = multf[sl] * dinv[(r << 12) + sl];
            swl[s16][idx] = w;
            swsum += w;
        }
        for (int o = 32; o; o >>= 1) swsum += __shfl_down(swsum, o);
        if (lane == 0) ssw[s16] = swsum;
    }
    __syncthreads();
    // aggregate: wave wv owns slots base+4wv .. +3; lane covers 4 cols (float4)
    int c4 = lane << 2;
    for (int j = 0; j < 4; ++j) {
        int s16 = (wv << 2) + j;
        int slot = base + s16;
        if (slot >= U) { *(float4*)&ys[s16][c4] = make_float4(0.f, 0.f, 0.f, 0.f); continue; }
        int n = sn[s16];
        float di = sdii[s16];
        float4 v = ((const float4*)(feat + (size_t)nodeof[slot] * IN_DIM))[lane];
        float4 acc;
        acc.x = di * v.x; acc.y = di * v.y; acc.z = di * v.z; acc.w = di * v.w;
        #pragma unroll 4
        for (int k = 0; k < n; ++k) {
            float w = swl[s16][k];
            float4 x = ((const float4*)(feat + (size_t)snode[s16][k] * IN_DIM))[lane];
            acc.x += w * x.x; acc.y += w * x.y; acc.z += w * x.z; acc.w += w * x.w;
        }
        float f = di * (di + ssw[s16]);
        float4 a4 = *(const float4*)(af + c4);
        float4 b4 = *(const float4*)(bfv + c4);
        float4 o;
        o.x = a4.x * (acc.x * di) + b4.x * f;
        o.y = a4.y * (acc.y * di) + b4.y * f;
        o.z = a4.z * (acc.z * di) + b4.z * f;
        o.w = a4.w * (acc.w * di) + b4.w * f;
        *(float4*)&ys[s16][c4] = o;
    }
    __syncthreads();
    // MLP: thread -> col c = t&127, group g = t>>7 covers slots g*8..g*8+7
    int c = t & 127, g = t >> 7;
    float acc[8] = {0.f};
    for (int k = 0; k < IN_DIM; ++k) {
        float wvl = w1[k * HID + c];
        #pragma unroll
        for (int j = 0; j < 8; ++j) acc[j] += ys[g * 8 + j][k] * wvl;
    }
    #pragma unroll
    for (int j = 0; j < 8; ++j) {
        int slot = base + g * 8 + j;
        if (slot < U) {
            float z = acc[j];
            float e = z > 0.f ? z : expm1f(z);            // elu
            h1[((size_t)(r << 12) + slot) * HID + c] = 1.f / (1.f + expf(-e));  // sigmoid
        }
    }
}

// ---- fused agg2+mlp2: 16 slots/block; agg h1 -> LDS -> GEMM + elu ----
__global__ __launch_bounds__(256) void aggmlp2_k(const float* __restrict__ h1,
                                                 const unsigned* __restrict__ cols,
                                                 const int* __restrict__ cnt,
                                                 const float* __restrict__ dinv,
                                                 const float* __restrict__ multf,
                                                 const int* __restrict__ Ucnt,
                                                 const float* __restrict__ w2,
                                                 float* __restrict__ h2) {
    int blk = blockIdx.x;                 // r*256 + chunk
    int r = blk >> 8, base = (blk & 255) << 4;
    int U = *Ucnt;
    if (base >= U) return;
    int t = threadIdx.x, lane = t & 63, wv = t >> 6;
    __shared__ unsigned short scl[16][CAPD];     // 4 KB (slot ids)
    __shared__ float swl[16][CAPD];              // 8 KB
    __shared__ float ys[16][HID];                // 8 KB
    __shared__ float sdii[16];
    __shared__ int sn[16];
    for (int s16 = wv; s16 < 16; s16 += 4) {
        int slot = base + s16;
        int n = (slot < U) ? cnt[(r << 12) + slot] : 0;
        if (lane == 0) { sn[s16] = n; sdii[s16] = (slot < U) ? dinv[(r << 12) + slot] : 0.f; }
        size_t cb = ((size_t)(r << 12) + slot) * CAPD;
        for (int idx = lane; idx < n; idx += 64) {
            unsigned e = cols[cb + idx];
            int sl = e >> 13;
            scl[s16][idx] = (unsigned short)sl;
            swl[s16][idx] = multf[sl] * dinv[(r << 12) + sl];
        }
    }
    __syncthreads();
    const float* h1r = h1 + ((size_t)(r << 12)) * HID;
    int c2 = lane << 1;
    for (int j = 0; j < 4; ++j) {
        int s16 = (wv << 2) + j;
        int slot = base + s16;
        if (slot >= U) { ys[s16][c2] = 0.f; ys[s16][c2 + 1] = 0.f; continue; }
        int n = sn[s16];
        float di = sdii[s16];
        float2 v = ((const float2*)(h1r + (size_t)slot * HID))[lane];
        float ax = di * v.x, ay = di * v.y;
        #pragma unroll 4
        for (int k = 0; k < n; ++k) {
            float w = swl[s16][k];
            float2 x = ((const float2*)(h1r + (size_t)scl[s16][k] * HID))[lane];
            ax += w * x.x; ay += w * x.y;
        }
        ys[s16][c2] = ax * di;
        ys[s16][c2 + 1] = ay * di;
    }
    __syncthreads();
    // MLP2: thread -> col c = t&63, group g = t>>6 covers slots g*4..g*4+3
    int c = t & 63, g = t >> 6;
    float acc[4] = {0.f};
    for (int k = 0; k < HID; ++k) {
        float wvl = w2[k * OUT + c];
        #pragma unroll
        for (int j = 0; j < 4; ++j) acc[j] += ys[g * 4 + j][k] * wvl;
    }
    #pragma unroll
    for (int j = 0; j < 4; ++j) {
        int slot = base + g * 4 + j;
        if (slot < U) {
            float z = acc[j];
            h2[((size_t)(r << 12) + slot) * OUT + c] = z > 0.f ? z : expm1f(z);  // elu
        }
    }
}

// ---- BN2 stats per (relation, column): multiplicity-weighted over slots ----
__global__ __launch_bounds__(256) void bn2_stats_k(const float* __restrict__ h2,
                                                   const float* __restrict__ multf,
                                                   const int* __restrict__ Ucnt,
                                                   float* __restrict__ m2,
                                                   float* __restrict__ rs2) {
    int ro = blockIdx.x;             // r*OUT + o
    int r = ro >> 6, o = ro & (OUT - 1);
    int U = *Ucnt;
    float s = 0.f, q = 0.f;
    for (int sl = threadIdx.x; sl < U; sl += 256) {
        float m = multf[sl];
        float v = h2[(size_t)((r << 12) + sl) * OUT + o];
        s += m * v; q += m * v * v;
    }
    int lane = threadIdx.x & 63, wv = threadIdx.x >> 6;
    for (int off = 32; off; off >>= 1) { s += __shfl_down(s, off); q += __shfl_down(q, off); }
    __shared__ float ps[4], pq[4];
    if (lane == 0) { ps[wv] = s; pq[wv] = q; }
    __syncthreads();
    if (threadIdx.x == 0) {
        float S = ps[0] + ps[1] + ps[2] + ps[3];
        float Q = pq[0] + pq[1] + pq[2] + pq[3];
        float m = S / BB;                 // sum of mult == BB positions
        float v = Q / BB - m * m;
        m2[ro] = m;
        rs2[ro] = rsqrtf(v + EPS);
    }
}

// ---- finalize: out[i] = relu(mean_r BN2(h2[r, slot(i)])) ----
__global__ __launch_bounds__(256) void finalize_k(const float* __restrict__ h2,
                                                  const unsigned short* __restrict__ pos2slot,
                                                  const float* __restrict__ m2,
                                                  const float* __restrict__ rs2,
                                                  const float* __restrict__ g2,
                                                  const float* __restrict__ b2,
                                                  float* __restrict__ out) {
    int idx = blockIdx.x * 256 + threadIdx.x;  // i*OUT + o
    if (idx >= BB * OUT) return;
    int i = idx >> 6, o = idx & (OUT - 1);
    int sl = pos2slot[i];
    float s = 0.f;
    for (int r = 0; r < RR; ++r) {
        float v = h2[(size_t)((r << 12) + sl) * OUT + o];
        s += (v - m2[r * OUT + o]) * rs2[r * OUT + o] * g2[o] + b2[o];
    }
    s *= (1.0f / RR);
    out[idx] = s > 0.f ? s : 0.f;
}

extern "C" void kernel_launch(void* const* d_in, const int* in_sizes, int n_in,
                              void* d_out, int out_size, void* d_ws, size_t ws_size,
                              hipStream_t stream) {
    const float* feat = (const float*)d_in[0];
    const float* adj  = (const float*)d_in[1];
    const int*   bn   = (const int*)d_in[2];
    const float* w1   = (const float*)d_in[3];
    const float* w2   = (const float*)d_in[4];
    const float* g1   = (const float*)d_in[5];
    const float* b1   = (const float*)d_in[6];
    const float* g2   = (const float*)d_in[7];
    const float* b2   = (const float*)d_in[8];
    float* out = (float*)d_out;

    // workspace layout (256-aligned offsets)
    char* ws = (char*)d_ws;
    size_t off = 0;
    auto alloc = [&](size_t bytes) { size_t o = off; off += (bytes + 255) & ~(size_t)255; return o; };
    unsigned long long* memb = (unsigned long long*)(ws + alloc(MWN * 8));      // 1 KB
    unsigned short* rankg    = (unsigned short*)(ws + alloc(NN * 2));           // 16 KB
    unsigned short* nodeof   = (unsigned short*)(ws + alloc(BB * 2));           // 8 KB
    float* multf             = (float*)(ws + alloc(BB * 4));                    // 16 KB
    int* Ucnt                = (int*)(ws + alloc(4));
    unsigned short* pos2slot = (unsigned short*)(ws + alloc(BB * 2));           // 8 KB
    float* af                = (float*)(ws + alloc(IN_DIM * 4));
    float* bfv               = (float*)(ws + alloc(IN_DIM * 4));
    float* m2                = (float*)(ws + alloc(RR * OUT * 4));
    float* rs2               = (float*)(ws + alloc(RR * OUT * 4));
    unsigned* cols           = (unsigned*)(ws + alloc((size_t)RR * BB * CAPD * 4)); // 6.3 MB
    int* cnt                 = (int*)(ws + alloc((size_t)RR * BB * 4));         // 48 KB
    float* dinv              = (float*)(ws + alloc((size_t)RR * BB * 4));       // 48 KB
    float* h1                = (float*)(ws + alloc((size_t)RR * BB * HID * 4)); // 6.3 MB
    float* h2                = (float*)(ws + alloc((size_t)RR * BB * OUT * 4)); // 3.1 MB

    k1_bn1_prep_k<<<IN_DIM + 1, 256, 0, stream>>>(feat, bn, g1, b1, af, bfv,
                                                  memb, rankg, nodeof, multf, Ucnt, pos2slot);
    build_k<<<RR * BB, 256, 0, stream>>>(adj, nodeof, Ucnt, memb, rankg, multf, cols, cnt, dinv);
    aggmlp1_k<<<RR * (BB / 16), 256, 0, stream>>>(feat, cols, cnt, dinv, multf, nodeof, Ucnt,
                                                  af, bfv, w1, h1);
    aggmlp2_k<<<RR * (BB / 16), 256, 0, stream>>>(h1, cols, cnt, dinv, multf, Ucnt, w2, h2);
    bn2_stats_k<<<RR * OUT, 256, 0, stream>>>(h2, multf, Ucnt, m2, rs2);
    finalize_k<<<(BB * OUT + 255) / 256, 256, 0, stream>>>(h2, pos2slot, m2, rs2, g2, b2, out);
}